// Round 1
// baseline (17077.878 us; speedup 1.0000x reference)
//
#include <hip/hip_runtime.h>
#include <hip/hip_bf16.h>

#define NB 512
#define NT 128
#define NE 256
#define ND 256

__device__ __forceinline__ float fast_tanh(float x) {
    x = fminf(fmaxf(x, -15.f), 15.f);
    float e = __expf(2.f * x);
    return 1.f - __fdividef(2.f, e + 1.f);
}
__device__ __forceinline__ float fast_sigm(float x) {
    x = fminf(fmaxf(x, -30.f), 30.f);
    float e = __expf(-x);
    return __fdividef(1.f, 1.f + e);
}
__device__ __forceinline__ void fma4(float4& a, float s, const float4 b) {
    a.x += s * b.x; a.y += s * b.y; a.z += s * b.z; a.w += s * b.w;
}

// P1: w1hT[j][i] = attn_w1[i][j] for i<512 (hc part); bias_g = b_ih + b_hh
__global__ __launch_bounds__(256) void prep_small(
    const float* __restrict__ w1, const float* __restrict__ bih,
    const float* __restrict__ bhh, float* __restrict__ w1hT,
    float* __restrict__ bias_g)
{
    const int t = threadIdx.x, blk = blockIdx.x;
    if (blk < 512) {
        w1hT[(size_t)t * 512 + blk] = w1[(size_t)blk * 256 + t];
    } else {
        for (int g = t; g < 1024; g += 256) bias_g[g] = bih[g] + bhh[g];
    }
}

// P2: pre[row][j] = b1[j] + sum_i enc[row][i] * attn_w1[512+i][j]
// row = b*NT + t flattened (65536 rows). 8 rows per block.
__global__ __launch_bounds__(256) void pre_enc_kernel(
    const float* __restrict__ enc, const float* __restrict__ w1,
    const float* __restrict__ b1, float* __restrict__ pre)
{
    __shared__ __align__(16) float encs[8][256];
    const int t = threadIdx.x;
    const size_t r0 = (size_t)blockIdx.x * 8;
    for (int k = t; k < 512; k += 256) {
        const int rl = k >> 6, i4 = (k & 63) * 4;
        *(float4*)&encs[rl][i4] = *(const float4*)(enc + (r0 + rl) * 256 + i4);
    }
    __syncthreads();
    const int rl = t >> 5;          // 0..7 rows
    const int j0 = (t & 31) * 8;    // 8 columns per thread
    float4 a0 = *(const float4*)(b1 + j0);
    float4 a1 = *(const float4*)(b1 + j0 + 4);
    const float* wp = w1 + (size_t)512 * 256 + j0;
    #pragma unroll 2
    for (int i = 0; i < 256; i += 4) {
        const float4 e4 = *(const float4*)&encs[rl][i];
        const float* w_i = wp + (size_t)i * 256;
        float4 wa, wb;
        wa = *(const float4*)(w_i);        wb = *(const float4*)(w_i + 4);
        fma4(a0, e4.x, wa); fma4(a1, e4.x, wb);
        wa = *(const float4*)(w_i + 256);  wb = *(const float4*)(w_i + 260);
        fma4(a0, e4.y, wa); fma4(a1, e4.y, wb);
        wa = *(const float4*)(w_i + 512);  wb = *(const float4*)(w_i + 516);
        fma4(a0, e4.z, wa); fma4(a1, e4.z, wb);
        wa = *(const float4*)(w_i + 768);  wb = *(const float4*)(w_i + 772);
        fma4(a0, e4.w, wa); fma4(a1, e4.w, wb);
    }
    float* op = pre + (r0 + rl) * 256 + j0;
    *(float4*)op = a0;
    *(float4*)(op + 4) = a1;
}

// Main: one WG per 2 batch rows, full 128-step scan. 512 threads (8 waves).
__global__ __launch_bounds__(512) void decoder_main(
    const float* __restrict__ enc, const float* __restrict__ yhist,
    const float* __restrict__ pre, const float* __restrict__ w1hT,
    const float* __restrict__ w2g, const float* __restrict__ whh,
    const float* __restrict__ wih, const float* __restrict__ biasg,
    const float* __restrict__ fcw, const float* __restrict__ fcb,
    const float* __restrict__ fcfw, const float* __restrict__ fcfb,
    float* __restrict__ out)
{
    __shared__ __align__(16) float hc[2][512];       // [row][h(256), c(256)]
    __shared__ __align__(16) float prehc[2][256];
    __shared__ __align__(16) float scores[2][128];
    __shared__ __align__(16) float attnw[2][128];
    __shared__ __align__(16) float ctxp[4][2][256];
    __shared__ __align__(16) float ctx[2][256];
    __shared__ __align__(16) float w2s[256];
    __shared__ __align__(16) float fcws[260];
    __shared__ __align__(16) float wihs[1024];
    __shared__ __align__(16) float biass[1024];
    __shared__ float red[8];
    __shared__ float ytil[2];
    __shared__ float pad_[14336];    // LDS > 80 KB => max 1 WG/CU

    const int t = threadIdx.x;
    const int b0 = blockIdx.x * 2;

    for (int k = t; k < 1024; k += 512) {
        ((float*)hc)[k] = 0.f;
        wihs[k]  = wih[k];
        biass[k] = biasg[k];
    }
    if (t < 256) w2s[t] = w2g[t];
    if (t < 257) fcws[t] = fcw[t];
    if (out == nullptr) pad_[t] = 1.f;   // unprovable; keeps pad_ allocated
    __syncthreads();

    #pragma unroll 1
    for (int ts = 0; ts < NT; ++ts) {
        // ---- A: prehc[r][j] = sum_i hc[r][i] * W1_hc[i][j]  (K=512)
        {
            const int r = t >> 8, j = t & 255;
            const float* wrow = w1hT + (size_t)j * 512;
            float acc = 0.f;
            #pragma unroll 4
            for (int i = 0; i < 512; i += 4) {
                const float4 w4 = *(const float4*)(wrow + i);
                const float4 h4 = *(const float4*)&hc[r][i];
                acc += h4.x * w4.x + h4.y * w4.y + h4.z * w4.z + h4.w * w4.w;
            }
            prehc[r][j] = acc;
        }
        __syncthreads();

        // ---- B: scores[r][s] = sum_j tanh(prehc[r][j] + pre_enc[b][s][j]) * w2[j]
        {
            const int s = t >> 2, q4 = (t & 3) * 4;
            #pragma unroll
            for (int r = 0; r < 2; ++r) {
                const float* pe = pre + ((size_t)(b0 + r) * NT + s) * NE + q4;
                float acc = 0.f;
                #pragma unroll
                for (int jj = 0; jj < 16; ++jj) {
                    const float4 p4 = *(const float4*)(pe + jj * 16);
                    const float4 h4 = *(const float4*)&prehc[r][jj * 16 + q4];
                    const float4 wv = *(const float4*)&w2s[jj * 16 + q4];
                    acc += fast_tanh(p4.x + h4.x) * wv.x;
                    acc += fast_tanh(p4.y + h4.y) * wv.y;
                    acc += fast_tanh(p4.z + h4.z) * wv.z;
                    acc += fast_tanh(p4.w + h4.w) * wv.w;
                }
                acc += __shfl_xor(acc, 1);
                acc += __shfl_xor(acc, 2);
                if (q4 == 0) scores[r][s] = acc;
            }
        }
        __syncthreads();

        // ---- softmax over s (wave 0 -> row 0, wave 1 -> row 1)
        if (t < 128) {
            const int r = t >> 6, l = t & 63;
            const float s0 = scores[r][l], s1 = scores[r][l + 64];
            float m = fmaxf(s0, s1);
            #pragma unroll
            for (int off = 32; off; off >>= 1) m = fmaxf(m, __shfl_xor(m, off));
            const float e0 = __expf(s0 - m), e1 = __expf(s1 - m);
            float sum = e0 + e1;
            #pragma unroll
            for (int off = 32; off; off >>= 1) sum += __shfl_xor(sum, off);
            const float inv = __fdividef(1.f, sum);
            attnw[r][l]      = e0 * inv;
            attnw[r][l + 64] = e1 * inv;
        }
        __syncthreads();

        // ---- C: ctx[r][e] = sum_s attn[r][s] * enc[b][s][e]  (4 s-slices)
        {
            const int r = t >> 8, sh = (t >> 6) & 3, e4 = (t & 63) * 4;
            const float* ep = enc + ((size_t)(b0 + r) * NT + sh * 32) * NE + e4;
            float4 acc = make_float4(0.f, 0.f, 0.f, 0.f);
            #pragma unroll 4
            for (int s = 0; s < 32; ++s) {
                const float a = attnw[r][sh * 32 + s];
                const float4 v = *(const float4*)(ep + (size_t)s * NE);
                fma4(acc, a, v);
            }
            *(float4*)&ctxp[sh][r][e4] = acc;
        }
        __syncthreads();
        // ---- C2 + D: combine ctx, y_tilde = ctx . fc_w[0:256] (+ y_t, bias)
        {
            const int r = t >> 8, e = t & 255;
            const float v = ctxp[0][r][e] + ctxp[1][r][e] + ctxp[2][r][e] + ctxp[3][r][e];
            ctx[r][e] = v;
            float p = v * fcws[e];
            #pragma unroll
            for (int off = 32; off; off >>= 1) p += __shfl_xor(p, off);
            if ((t & 63) == 0) red[t >> 6] = p;
        }
        __syncthreads();
        if (t < 2) {
            const float s = red[t * 4] + red[t * 4 + 1] + red[t * 4 + 2] + red[t * 4 + 3];
            ytil[t] = s + yhist[(size_t)(b0 + t) * NT + ts] * fcws[256] + fcb[0];
        }
        __syncthreads();

        // ---- E: gates (4 dots of K=256 per thread, one d each) + pointwise
        {
            const int r = t >> 8, d = t & 255;
            const float* wi_ = whh + (size_t)d * 256;
            const float* wf_ = wi_ + 256 * 256;
            const float* wg_ = wi_ + 512 * 256;
            const float* wo_ = wi_ + 768 * 256;
            float ai = 0.f, af = 0.f, ag = 0.f, ao = 0.f;
            #pragma unroll 2
            for (int j = 0; j < 256; j += 4) {
                const float4 h4 = *(const float4*)&hc[r][j];
                const float4 a4 = *(const float4*)(wi_ + j);
                const float4 b4 = *(const float4*)(wf_ + j);
                const float4 c4 = *(const float4*)(wg_ + j);
                const float4 d4 = *(const float4*)(wo_ + j);
                ai += h4.x * a4.x + h4.y * a4.y + h4.z * a4.z + h4.w * a4.w;
                af += h4.x * b4.x + h4.y * b4.y + h4.z * b4.z + h4.w * b4.w;
                ag += h4.x * c4.x + h4.y * c4.y + h4.z * c4.z + h4.w * c4.w;
                ao += h4.x * d4.x + h4.y * d4.y + h4.z * d4.z + h4.w * d4.w;
            }
            const float yt = ytil[r];
            const float gi = ai + yt * wihs[d]       + biass[d];
            const float gf = af + yt * wihs[256 + d] + biass[256 + d];
            const float gg = ag + yt * wihs[512 + d] + biass[512 + d];
            const float go = ao + yt * wihs[768 + d] + biass[768 + d];
            const float c_old = hc[r][256 + d];
            const float cn = fast_sigm(gf) * c_old + fast_sigm(gi) * fast_tanh(gg);
            const float hn = fast_sigm(go) * fast_tanh(cn);
            __syncthreads();               // drain all reads of h before overwrite
            hc[r][d] = hn;
            hc[r][256 + d] = cn;
        }
        __syncthreads();
    }

    // ---- final: out[b] = [h, ctx] . fcf_w + fcf_b
    {
        const int r = t >> 8, j = t & 255;
        float p = hc[r][j] * fcfw[j] + ctx[r][j] * fcfw[256 + j];
        #pragma unroll
        for (int off = 32; off; off >>= 1) p += __shfl_xor(p, off);
        if ((t & 63) == 0) red[t >> 6] = p;
    }
    __syncthreads();
    if (t < 2)
        out[b0 + t] = red[t * 4] + red[t * 4 + 1] + red[t * 4 + 2] + red[t * 4 + 3] + fcfb[0];
}

extern "C" void kernel_launch(void* const* d_in, const int* in_sizes, int n_in,
                              void* d_out, int out_size, void* d_ws, size_t ws_size,
                              hipStream_t stream) {
    (void)in_sizes; (void)n_in; (void)out_size; (void)ws_size;
    const float* enc   = (const float*)d_in[0];   // [512][128][256]
    const float* yhist = (const float*)d_in[1];   // [512][128]
    const float* w1    = (const float*)d_in[2];   // [768][256]
    const float* b1    = (const float*)d_in[3];   // [256]
    const float* w2    = (const float*)d_in[4];   // [256]
    // d_in[5] = attn_b2: softmax-invariant, unused
    const float* wih   = (const float*)d_in[6];   // [1024]
    const float* whh   = (const float*)d_in[7];   // [1024][256]
    const float* bih   = (const float*)d_in[8];   // [1024]
    const float* bhh   = (const float*)d_in[9];   // [1024]
    const float* fcw   = (const float*)d_in[10];  // [257]
    const float* fcb   = (const float*)d_in[11];  // [1]
    const float* fcfw  = (const float*)d_in[12];  // [512]
    const float* fcfb  = (const float*)d_in[13];  // [1]
    float* out = (float*)d_out;

    float* ws    = (float*)d_ws;
    float* pre   = ws;                               // 16777216 floats (64 MB)
    float* w1hT  = ws + 16777216;                    // 131072 floats
    float* biasg = ws + 16777216 + 131072;           // 1024 floats

    prep_small<<<513, 256, 0, stream>>>(w1, bih, bhh, w1hT, biasg);
    pre_enc_kernel<<<8192, 256, 0, stream>>>(enc, w1, b1, pre);
    decoder_main<<<256, 512, 0, stream>>>(enc, yhist, pre, w1hT, w2, whh, wih,
                                          biasg, fcw, fcb, fcfw, fcfb, out);
}

// Round 2
// 8372.661 us; speedup vs baseline: 2.0397x; 2.0397x over previous
//
#include <hip/hip_runtime.h>
#include <hip/hip_bf16.h>

#define NT 128
#define NE 256
#define ND 256
#define R  4

__device__ __forceinline__ float fast_tanh(float x) {
    // 1 - 2/(e^{2x}+1); inf-safe without clamps (rcp(inf)=0)
    const float e = __expf(2.f * x);
    return __builtin_fmaf(-2.f, __fdividef(1.f, e + 1.f), 1.f);
}
__device__ __forceinline__ float fast_sigm(float x) {
    return __fdividef(1.f, 1.f + __expf(-x));
}
__device__ __forceinline__ void fma4(float4& a, float s, const float4 b) {
    a.x += s * b.x; a.y += s * b.y; a.z += s * b.z; a.w += s * b.w;
}

// ---- one-time transpose whh[1024][256] -> whhT[256][1024], coalesced both sides
__global__ __launch_bounds__(256) void transpose_whh(
    const float* __restrict__ whh, float* __restrict__ whhT)
{
    __shared__ float tile[64][65];
    const int t = threadIdx.x;
    const int bi = blockIdx.x >> 2;   // gd block (16)
    const int bj = blockIdx.x & 3;    // j block (4)
    #pragma unroll
    for (int k = 0; k < 16; ++k) {
        const int idx = k * 256 + t, r = idx >> 6, c = idx & 63;
        tile[r][c] = whh[(size_t)(bi * 64 + r) * 256 + bj * 64 + c];
    }
    __syncthreads();
    #pragma unroll
    for (int k = 0; k < 16; ++k) {
        const int idx = k * 256 + t, r = idx >> 6, c = idx & 63;
        whhT[(size_t)(bj * 64 + r) * 1024 + bi * 64 + c] = tile[c][r];
    }
}

// ---- pre[row][j] = b1[j] + sum_i enc[row][i] * attn_w1[512+i][j]
__global__ __launch_bounds__(256) void pre_enc_kernel(
    const float* __restrict__ enc, const float* __restrict__ w1,
    const float* __restrict__ b1, float* __restrict__ pre)
{
    __shared__ __align__(16) float encs[8][256];
    const int t = threadIdx.x;
    const size_t r0 = (size_t)blockIdx.x * 8;
    for (int k = t; k < 512; k += 256) {
        const int rl = k >> 6, i4 = (k & 63) * 4;
        *(float4*)&encs[rl][i4] = *(const float4*)(enc + (r0 + rl) * 256 + i4);
    }
    __syncthreads();
    const int rl = t >> 5;
    const int j0 = (t & 31) * 8;
    float4 a0 = *(const float4*)(b1 + j0);
    float4 a1 = *(const float4*)(b1 + j0 + 4);
    const float* wp = w1 + (size_t)512 * 256 + j0;
    #pragma unroll 2
    for (int i = 0; i < 256; i += 4) {
        const float4 e4 = *(const float4*)&encs[rl][i];
        const float* w_i = wp + (size_t)i * 256;
        float4 wa, wb;
        wa = *(const float4*)(w_i);        wb = *(const float4*)(w_i + 4);
        fma4(a0, e4.x, wa); fma4(a1, e4.x, wb);
        wa = *(const float4*)(w_i + 256);  wb = *(const float4*)(w_i + 260);
        fma4(a0, e4.y, wa); fma4(a1, e4.y, wb);
        wa = *(const float4*)(w_i + 512);  wb = *(const float4*)(w_i + 516);
        fma4(a0, e4.z, wa); fma4(a1, e4.z, wb);
        wa = *(const float4*)(w_i + 768);  wb = *(const float4*)(w_i + 772);
        fma4(a0, e4.w, wa); fma4(a1, e4.w, wb);
    }
    float* op = pre + (r0 + rl) * 256 + j0;
    *(float4*)op = a0;
    *(float4*)(op + 4) = a1;
}

// ---- main scan: 128 WGs x 1024 threads, 4 batch rows per WG.
__global__ __launch_bounds__(1024) void decoder_main(
    const float* __restrict__ enc, const float* __restrict__ yhist,
    const float* __restrict__ pre, const float* __restrict__ w1,
    const float* __restrict__ w2g, const float* __restrict__ whhT,
    const float* __restrict__ wih, const float* __restrict__ bih,
    const float* __restrict__ bhh, const float* __restrict__ fcw,
    const float* __restrict__ fcb, const float* __restrict__ fcfw,
    const float* __restrict__ fcfb, float* __restrict__ out)
{
    __shared__ __align__(16) float hc4[512][4];    // [i][r], i<256 h, i>=256 c
    __shared__ __align__(16) float prehc[4][256];
    __shared__ __align__(16) float part[16384];    // union: partA / ctxp / partE
    __shared__ __align__(16) float scores[4][128];
    __shared__ __align__(16) float attnw[4][128];
    __shared__ __align__(16) float ctx[4][256];
    __shared__ __align__(16) float w2s[256];
    __shared__ __align__(16) float fcws[258];      // fcw[257] + fcb
    __shared__ __align__(16) float wihs[1024];
    __shared__ __align__(16) float biass[1024];
    __shared__ float red[16];
    __shared__ float ytil[4];

    const int t = threadIdx.x;
    const int lane = t & 63;
    const int wv = t >> 6;           // wave 0..15
    const int b0 = blockIdx.x * R;

    // init
    for (int k = t; k < 2048; k += 1024) ((float*)hc4)[k] = 0.f;
    wihs[t & 1023] = wih[t & 1023];          // each of first 1024 threads = all
    biass[t & 1023] = bih[t & 1023] + bhh[t & 1023];
    if (t < 256) w2s[t] = w2g[t];
    if (t < 258) fcws[t] = (t < 257) ? fcw[t] : fcb[0];
    __syncthreads();

    #pragma unroll 1
    for (int ts = 0; ts < NT; ++ts) {
        // ---- A: partial prehc. wave wv covers i in [wv*32, wv*32+32), all 256 j.
        {
            float4 a0 = {0,0,0,0}, a1 = {0,0,0,0}, a2 = {0,0,0,0}, a3 = {0,0,0,0};
            const float* wp = w1 + (size_t)(wv * 32) * 256 + lane * 4;
            const float4* hp = (const float4*)&hc4[wv * 32][0];
            #pragma unroll 4
            for (int i = 0; i < 32; ++i) {
                const float4 wvv = *(const float4*)(wp + (size_t)i * 256); // coalesced 1KB/wave
                const float4 h4 = hp[i];                                   // broadcast
                fma4(a0, h4.x, wvv); fma4(a1, h4.y, wvv);
                fma4(a2, h4.z, wvv); fma4(a3, h4.w, wvv);
            }
            const int pb = (wv * 4) * 256 + lane * 4;
            *(float4*)&part[pb]           = a0;
            *(float4*)&part[pb + 256]     = a1;
            *(float4*)&part[pb + 512]     = a2;
            *(float4*)&part[pb + 768]     = a3;
        }
        __syncthreads();
        // ---- reduce A: 1024 threads own (r,j)
        {
            const int r = t >> 8, j = t & 255;
            float s = 0.f;
            #pragma unroll
            for (int w = 0; w < 16; ++w) s += part[(w * 4 + r) * 256 + j];
            prehc[r][j] = s;
        }
        __syncthreads();

        // ---- B: scores[r][s] = sum_j tanh(prehc+pre)*w2. thread = (s, jc)
        {
            const int s = t >> 3, jc = t & 7;
            const float* p0 = pre + ((size_t)(b0 + 0) * NT + s) * NE + jc * 4;
            const float* p1 = pre + ((size_t)(b0 + 1) * NT + s) * NE + jc * 4;
            const float* p2 = pre + ((size_t)(b0 + 2) * NT + s) * NE + jc * 4;
            const float* p3 = pre + ((size_t)(b0 + 3) * NT + s) * NE + jc * 4;
            float a0 = 0.f, a1 = 0.f, a2 = 0.f, a3 = 0.f;
            #pragma unroll
            for (int i = 0; i < 8; ++i) {
                const int j = i * 32 + jc * 4;
                const float4 wv4 = *(const float4*)&w2s[j];
                const float4 h0 = *(const float4*)&prehc[0][j];
                const float4 h1 = *(const float4*)&prehc[1][j];
                const float4 h2 = *(const float4*)&prehc[2][j];
                const float4 h3 = *(const float4*)&prehc[3][j];
                const float4 q0 = *(const float4*)(p0 + i * 32);
                const float4 q1 = *(const float4*)(p1 + i * 32);
                const float4 q2 = *(const float4*)(p2 + i * 32);
                const float4 q3 = *(const float4*)(p3 + i * 32);
                a0 += fast_tanh(q0.x + h0.x) * wv4.x + fast_tanh(q0.y + h0.y) * wv4.y
                    + fast_tanh(q0.z + h0.z) * wv4.z + fast_tanh(q0.w + h0.w) * wv4.w;
                a1 += fast_tanh(q1.x + h1.x) * wv4.x + fast_tanh(q1.y + h1.y) * wv4.y
                    + fast_tanh(q1.z + h1.z) * wv4.z + fast_tanh(q1.w + h1.w) * wv4.w;
                a2 += fast_tanh(q2.x + h2.x) * wv4.x + fast_tanh(q2.y + h2.y) * wv4.y
                    + fast_tanh(q2.z + h2.z) * wv4.z + fast_tanh(q2.w + h2.w) * wv4.w;
                a3 += fast_tanh(q3.x + h3.x) * wv4.x + fast_tanh(q3.y + h3.y) * wv4.y
                    + fast_tanh(q3.z + h3.z) * wv4.z + fast_tanh(q3.w + h3.w) * wv4.w;
            }
            a0 += __shfl_xor(a0, 1); a0 += __shfl_xor(a0, 2); a0 += __shfl_xor(a0, 4);
            a1 += __shfl_xor(a1, 1); a1 += __shfl_xor(a1, 2); a1 += __shfl_xor(a1, 4);
            a2 += __shfl_xor(a2, 1); a2 += __shfl_xor(a2, 2); a2 += __shfl_xor(a2, 4);
            a3 += __shfl_xor(a3, 1); a3 += __shfl_xor(a3, 2); a3 += __shfl_xor(a3, 4);
            if (jc == 0) {
                scores[0][s] = a0; scores[1][s] = a1;
                scores[2][s] = a2; scores[3][s] = a3;
            }
        }
        __syncthreads();

        // ---- softmax (waves 0..3, one per row)
        if (t < 256) {
            const int r = wv;
            const float s0 = scores[r][lane], s1 = scores[r][lane + 64];
            float m = fmaxf(s0, s1);
            #pragma unroll
            for (int off = 32; off; off >>= 1) m = fmaxf(m, __shfl_xor(m, off));
            const float e0 = __expf(s0 - m), e1 = __expf(s1 - m);
            float sum = e0 + e1;
            #pragma unroll
            for (int off = 32; off; off >>= 1) sum += __shfl_xor(sum, off);
            const float inv = __fdividef(1.f, sum);
            attnw[r][lane] = e0 * inv;
            attnw[r][lane + 64] = e1 * inv;
        }
        __syncthreads();

        // ---- C: ctx partials. thread = (r, s-slice, e4)
        {
            const int r = t >> 8, sl = (t >> 6) & 3, e4 = (t & 63) * 4;
            const float* ep = enc + ((size_t)(b0 + r) * NT + sl * 32) * NE + e4;
            float4 acc = {0.f, 0.f, 0.f, 0.f};
            #pragma unroll 4
            for (int s2 = 0; s2 < 32; ++s2) {
                const float a = attnw[r][sl * 32 + s2];
                fma4(acc, a, *(const float4*)(ep + (size_t)s2 * NE));
            }
            *(float4*)&part[((sl * 4 + r) << 8) + e4] = acc;
        }
        __syncthreads();
        // ---- reduce C + y_tilde partial
        {
            const int r = t >> 8, e = t & 255;
            const float v = part[(r) * 256 + e] + part[(4 + r) * 256 + e]
                          + part[(8 + r) * 256 + e] + part[(12 + r) * 256 + e];
            ctx[r][e] = v;
            float p = v * fcws[e];
            #pragma unroll
            for (int off = 32; off; off >>= 1) p += __shfl_xor(p, off);
            if (lane == 0) red[wv] = p;
        }
        __syncthreads();

        // ---- E: gate partials (coalesced whhT stream) + ytil finalize
        {
            if (t < 4)
                ytil[t] = red[4 * t] + red[4 * t + 1] + red[4 * t + 2] + red[4 * t + 3]
                        + yhist[(size_t)(b0 + t) * NT + ts] * fcws[256] + fcws[257];
            const int jc = wv >> 2, gb = wv & 3;
            float4 a0 = {0,0,0,0}, a1 = {0,0,0,0}, a2 = {0,0,0,0}, a3 = {0,0,0,0};
            const float* wp = whhT + (size_t)(jc * 64) * 1024 + gb * 256 + lane * 4;
            const float4* hp = (const float4*)&hc4[jc * 64][0];
            #pragma unroll 4
            for (int i = 0; i < 64; ++i) {
                const float4 wv4 = *(const float4*)(wp + (size_t)i * 1024); // coalesced
                const float4 h4 = hp[i];                                    // broadcast
                fma4(a0, h4.x, wv4); fma4(a1, h4.y, wv4);
                fma4(a2, h4.z, wv4); fma4(a3, h4.w, wv4);
            }
            const int pb = (jc * 4) * 1024 + gb * 256 + lane * 4;
            *(float4*)&part[pb]          = a0;
            *(float4*)&part[pb + 1024]   = a1;
            *(float4*)&part[pb + 2048]   = a2;
            *(float4*)&part[pb + 3072]   = a3;
        }
        __syncthreads();
        // ---- reduce E + LSTM pointwise. thread = (r, d)
        {
            const int r = t >> 8, d = t & 255;
            float g0 = 0.f, g1 = 0.f, g2 = 0.f, g3 = 0.f;
            #pragma unroll
            for (int jc = 0; jc < 4; ++jc) {
                const int base = (jc * 4 + r) * 1024 + d;
                g0 += part[base];
                g1 += part[base + 256];
                g2 += part[base + 512];
                g3 += part[base + 768];
            }
            const float yt = ytil[r];
            const float gi = g0 + yt * wihs[d]       + biass[d];
            const float gf = g1 + yt * wihs[256 + d] + biass[256 + d];
            const float gg = g2 + yt * wihs[512 + d] + biass[512 + d];
            const float go = g3 + yt * wihs[768 + d] + biass[768 + d];
            const float c_old = hc4[256 + d][r];
            const float cn = fast_sigm(gf) * c_old + fast_sigm(gi) * fast_tanh(gg);
            const float hn = fast_sigm(go) * fast_tanh(cn);
            hc4[d][r] = hn;          // each (r,d) cell owned by exactly one thread
            hc4[256 + d][r] = cn;
        }
        __syncthreads();
    }

    // ---- final: out[b] = [h, ctx] . fcf_w + fcf_b
    {
        const int r = t >> 8, j = t & 255;
        float p = hc4[j][r] * fcfw[j] + ctx[r][j] * fcfw[256 + j];
        #pragma unroll
        for (int off = 32; off; off >>= 1) p += __shfl_xor(p, off);
        if (lane == 0) red[wv] = p;
    }
    __syncthreads();
    if (t < 4)
        out[b0 + t] = red[4 * t] + red[4 * t + 1] + red[4 * t + 2] + red[4 * t + 3] + fcfb[0];
}

extern "C" void kernel_launch(void* const* d_in, const int* in_sizes, int n_in,
                              void* d_out, int out_size, void* d_ws, size_t ws_size,
                              hipStream_t stream) {
    (void)in_sizes; (void)n_in; (void)out_size; (void)ws_size;
    const float* enc   = (const float*)d_in[0];   // [512][128][256]
    const float* yhist = (const float*)d_in[1];   // [512][128]
    const float* w1    = (const float*)d_in[2];   // [768][256]
    const float* b1    = (const float*)d_in[3];   // [256]
    const float* w2    = (const float*)d_in[4];   // [256]
    // d_in[5] = attn_b2: softmax-invariant, unused
    const float* wih   = (const float*)d_in[6];   // [1024]
    const float* whh   = (const float*)d_in[7];   // [1024][256]
    const float* bih   = (const float*)d_in[8];   // [1024]
    const float* bhh   = (const float*)d_in[9];   // [1024]
    const float* fcw   = (const float*)d_in[10];  // [257]
    const float* fcb   = (const float*)d_in[11];  // [1]
    const float* fcfw  = (const float*)d_in[12];  // [512]
    const float* fcfb  = (const float*)d_in[13];  // [1]
    float* out = (float*)d_out;

    float* ws   = (float*)d_ws;
    float* pre  = ws;                 // 512*128*256 = 16777216 floats (64 MB)
    float* whhT = ws + 16777216;      // 256*1024 = 262144 floats (1 MB)

    transpose_whh<<<64, 256, 0, stream>>>(whh, whhT);
    pre_enc_kernel<<<8192, 256, 0, stream>>>(enc, w1, b1, pre);
    decoder_main<<<128, 1024, 0, stream>>>(enc, yhist, pre, w1, w2, whhT, wih,
                                           bih, bhh, fcw, fcb, fcfw, fcfb, out);
}

// Round 3
// 6356.666 us; speedup vs baseline: 2.6866x; 1.3171x over previous
//
#include <hip/hip_runtime.h>
#include <hip/hip_bf16.h>

#define NT 128
#define NE 256
#define ND 256

__device__ __forceinline__ float fast_tanh(float x) {
    const float e = __expf(2.f * x);
    return __builtin_fmaf(-2.f, __fdividef(1.f, e + 1.f), 1.f);
}
__device__ __forceinline__ float fast_sigm(float x) {
    return __fdividef(1.f, 1.f + __expf(-x));
}
__device__ __forceinline__ void fma4(float4& a, float s, const float4 b) {
    a.x += s * b.x; a.y += s * b.y; a.z += s * b.z; a.w += s * b.w;
}
__device__ __forceinline__ unsigned short f2bf(float f) {   // RNE
    unsigned int u = __float_as_uint(f);
    return (unsigned short)((u + 0x7FFFu + ((u >> 16) & 1u)) >> 16);
}
__device__ __forceinline__ float bf2f(unsigned short s) {
    return __uint_as_float(((unsigned int)s) << 16);
}

// ---- prep: w1 hc-half -> bf16 (blocks 0..511); bias sum (block 512)
__global__ __launch_bounds__(256) void prep_w1_bias(
    const float* __restrict__ w1, const float* __restrict__ bih,
    const float* __restrict__ bhh, unsigned short* __restrict__ w1bf,
    float* __restrict__ biasg)
{
    const int t = threadIdx.x, blk = blockIdx.x;
    if (blk < 512) {
        const int idx = blk * 256 + t;
        w1bf[idx] = f2bf(w1[idx]);
    } else {
        for (int g = t; g < 1024; g += 256) biasg[g] = bih[g] + bhh[g];
    }
}

// ---- transpose whh[1024][256] -> whhT_bf16[256][1024]
__global__ __launch_bounds__(256) void transpose_whh_bf(
    const float* __restrict__ whh, unsigned short* __restrict__ whhT)
{
    __shared__ float tile[64][65];
    const int t = threadIdx.x;
    const int bi = blockIdx.x >> 2;   // gd block (16)
    const int bj = blockIdx.x & 3;    // j block (4)
    #pragma unroll
    for (int k = 0; k < 16; ++k) {
        const int idx = k * 256 + t, r = idx >> 6, c = idx & 63;
        tile[r][c] = whh[(size_t)(bi * 64 + r) * 256 + bj * 64 + c];
    }
    __syncthreads();
    #pragma unroll
    for (int k = 0; k < 16; ++k) {
        const int idx = k * 256 + t, r = idx >> 6, c = idx & 63;
        whhT[(size_t)(bj * 64 + r) * 1024 + bi * 64 + c] = f2bf(tile[c][r]);
    }
}

// ---- pre[row][j] = b1[j] + sum_i enc[row][i] * attn_w1[512+i][j]  (fp32)
__global__ __launch_bounds__(256) void pre_enc_kernel(
    const float* __restrict__ enc, const float* __restrict__ w1,
    const float* __restrict__ b1, float* __restrict__ pre)
{
    __shared__ __align__(16) float encs[8][256];
    const int t = threadIdx.x;
    const size_t r0 = (size_t)blockIdx.x * 8;
    for (int k = t; k < 512; k += 256) {
        const int rl = k >> 6, i4 = (k & 63) * 4;
        *(float4*)&encs[rl][i4] = *(const float4*)(enc + (r0 + rl) * 256 + i4);
    }
    __syncthreads();
    const int rl = t >> 5;
    const int j0 = (t & 31) * 8;
    float4 a0 = *(const float4*)(b1 + j0);
    float4 a1 = *(const float4*)(b1 + j0 + 4);
    const float* wp = w1 + (size_t)512 * 256 + j0;
    #pragma unroll 2
    for (int i = 0; i < 256; i += 4) {
        const float4 e4 = *(const float4*)&encs[rl][i];
        const float* w_i = wp + (size_t)i * 256;
        float4 wa, wb;
        wa = *(const float4*)(w_i);        wb = *(const float4*)(w_i + 4);
        fma4(a0, e4.x, wa); fma4(a1, e4.x, wb);
        wa = *(const float4*)(w_i + 256);  wb = *(const float4*)(w_i + 260);
        fma4(a0, e4.y, wa); fma4(a1, e4.y, wb);
        wa = *(const float4*)(w_i + 512);  wb = *(const float4*)(w_i + 516);
        fma4(a0, e4.z, wa); fma4(a1, e4.z, wb);
        wa = *(const float4*)(w_i + 768);  wb = *(const float4*)(w_i + 772);
        fma4(a0, e4.w, wa); fma4(a1, e4.w, wb);
    }
    float* op = pre + (r0 + rl) * 256 + j0;
    *(float4*)op = a0;
    *(float4*)(op + 4) = a1;
}

// ---- main scan: 256 WGs x 1024 threads, 2 batch rows per WG (all CUs busy).
__global__ __launch_bounds__(1024, 4) void decoder_main(
    const float* __restrict__ enc, const float* __restrict__ yhist,
    const float* __restrict__ pre, const unsigned short* __restrict__ w1bf,
    const float* __restrict__ w2g, const unsigned short* __restrict__ whhT,
    const float* __restrict__ wih, const float* __restrict__ biasg,
    const float* __restrict__ fcw, const float* __restrict__ fcb,
    const float* __restrict__ fcfw, const float* __restrict__ fcfb,
    float* __restrict__ out)
{
    __shared__ __align__(16) float hc2[512][2];    // [i][r]: i<256 h, i>=256 c
    __shared__ __align__(16) float prehc[2][256];
    __shared__ __align__(16) float part[8192];     // union: A(32x256)/C(16x256)/E(8x1024)
    __shared__ __align__(16) float scores[2][128];
    __shared__ __align__(16) float attnw[2][128];
    __shared__ __align__(16) float ctx[2][256];
    __shared__ __align__(16) float w2s[256];
    __shared__ __align__(16) float fcws[258];      // fcw[257] + fcb
    __shared__ __align__(16) float wihs[1024];
    __shared__ __align__(16) float biass[1024];
    __shared__ float red[8];
    __shared__ float ytil[2];

    const int t = threadIdx.x;
    const int lane = t & 63;
    const int wv = t >> 6;           // wave 0..15
    const int b0 = blockIdx.x * 2;

    ((float*)hc2)[t] = 0.f;
    wihs[t] = wih[t];
    biass[t] = biasg[t];
    if (t < 256) w2s[t] = w2g[t];
    if (t < 258) fcws[t] = (t < 257) ? fcw[t] : fcb[0];
    __syncthreads();

    #pragma unroll 1
    for (int ts = 0; ts < NT; ++ts) {
        // ---- A: prehc partials. wave wv: i in [wv*32,+32), lane: j = lane*4..+3
        {
            float4 a0 = {0,0,0,0}, a1 = {0,0,0,0};
            const unsigned short* wp = w1bf + (size_t)(wv * 32) * 256 + lane * 4;
            #pragma unroll 8
            for (int i = 0; i < 32; ++i) {
                const ushort4 wq = *(const ushort4*)(wp + (size_t)i * 256);
                const float4 w4 = {bf2f(wq.x), bf2f(wq.y), bf2f(wq.z), bf2f(wq.w)};
                const float2 h2 = *(const float2*)&hc2[wv * 32 + i][0];  // broadcast
                fma4(a0, h2.x, w4);
                fma4(a1, h2.y, w4);
            }
            *(float4*)&part[(wv * 2 + 0) * 256 + lane * 4] = a0;
            *(float4*)&part[(wv * 2 + 1) * 256 + lane * 4] = a1;
        }
        __syncthreads();
        if (t < 512) {        // reduce A
            const int r = t >> 8, j = t & 255;
            float s = 0.f;
            #pragma unroll
            for (int w = 0; w < 16; ++w) s += part[(w * 2 + r) * 256 + j];
            prehc[r][j] = s;
        }
        __syncthreads();

        // ---- B: scores[r][s] = sum_j tanh(prehc+pre)*w2. thread = (s, jc)
        {
            const int s = t >> 3, jc = t & 7;
            const float* p0 = pre + ((size_t)(b0 + 0) * NT + s) * NE + jc * 4;
            const float* p1 = p0 + (size_t)NT * NE;
            float a0 = 0.f, a1 = 0.f;
            #pragma unroll
            for (int i = 0; i < 8; ++i) {
                const int j = i * 32 + jc * 4;
                const float4 wv4 = *(const float4*)&w2s[j];
                const float4 h0 = *(const float4*)&prehc[0][j];
                const float4 h1 = *(const float4*)&prehc[1][j];
                const float4 q0 = *(const float4*)(p0 + i * 32);
                const float4 q1 = *(const float4*)(p1 + i * 32);
                a0 += fast_tanh(q0.x + h0.x) * wv4.x + fast_tanh(q0.y + h0.y) * wv4.y
                    + fast_tanh(q0.z + h0.z) * wv4.z + fast_tanh(q0.w + h0.w) * wv4.w;
                a1 += fast_tanh(q1.x + h1.x) * wv4.x + fast_tanh(q1.y + h1.y) * wv4.y
                    + fast_tanh(q1.z + h1.z) * wv4.z + fast_tanh(q1.w + h1.w) * wv4.w;
            }
            a0 += __shfl_xor(a0, 1); a0 += __shfl_xor(a0, 2); a0 += __shfl_xor(a0, 4);
            a1 += __shfl_xor(a1, 1); a1 += __shfl_xor(a1, 2); a1 += __shfl_xor(a1, 4);
            if (jc == 0) { scores[0][s] = a0; scores[1][s] = a1; }
        }
        __syncthreads();

        // ---- softmax (waves 0..1, one per row)
        if (t < 128) {
            const int r = t >> 6, l = t & 63;
            const float s0 = scores[r][l], s1 = scores[r][l + 64];
            float m = fmaxf(s0, s1);
            #pragma unroll
            for (int off = 32; off; off >>= 1) m = fmaxf(m, __shfl_xor(m, off));
            const float e0 = __expf(s0 - m), e1 = __expf(s1 - m);
            float sum = e0 + e1;
            #pragma unroll
            for (int off = 32; off; off >>= 1) sum += __shfl_xor(sum, off);
            const float inv = __fdividef(1.f, sum);
            attnw[r][l] = e0 * inv;
            attnw[r][l + 64] = e1 * inv;
        }
        __syncthreads();

        // ---- C: ctx partials. thread = (r, sl, e4), 8 s-slices of 16
        {
            const int r = t >> 9, sl = (t >> 6) & 7, e4 = (t & 63) * 4;
            const float* ep = enc + ((size_t)(b0 + r) * NT + sl * 16) * NE + e4;
            float4 acc = {0.f, 0.f, 0.f, 0.f};
            #pragma unroll 4
            for (int s2 = 0; s2 < 16; ++s2) {
                fma4(acc, attnw[r][sl * 16 + s2], *(const float4*)(ep + (size_t)s2 * NE));
            }
            *(float4*)&part[(sl * 2 + r) * 256 + e4] = acc;
        }
        __syncthreads();
        if (t < 512) {        // reduce C + y_tilde partial
            const int r = t >> 8, e = t & 255;
            float v = 0.f;
            #pragma unroll
            for (int sl = 0; sl < 8; ++sl) v += part[(sl * 2 + r) * 256 + e];
            ctx[r][e] = v;
            float p = v * fcws[e];
            #pragma unroll
            for (int off = 32; off; off >>= 1) p += __shfl_xor(p, off);
            if (lane == 0) red[wv] = p;     // waves 0..7
        }
        __syncthreads();

        // ---- E: gate partials (bf16 whhT stream) + ytil finalize
        {
            if (t < 2)
                ytil[t] = red[4 * t] + red[4 * t + 1] + red[4 * t + 2] + red[4 * t + 3]
                        + yhist[(size_t)(b0 + t) * NT + ts] * fcws[256] + fcws[257];
            const int jc = wv >> 2, gb = wv & 3;   // i-chunk of 64, gate-block of 256
            float4 a0 = {0,0,0,0}, a1 = {0,0,0,0};
            const unsigned short* wp = whhT + (size_t)(jc * 64) * 1024 + gb * 256 + lane * 4;
            #pragma unroll 8
            for (int i = 0; i < 64; ++i) {
                const ushort4 wq = *(const ushort4*)(wp + (size_t)i * 1024);
                const float4 w4 = {bf2f(wq.x), bf2f(wq.y), bf2f(wq.z), bf2f(wq.w)};
                const float2 h2 = *(const float2*)&hc2[jc * 64 + i][0];  // broadcast
                fma4(a0, h2.x, w4);
                fma4(a1, h2.y, w4);
            }
            *(float4*)&part[(jc * 2 + 0) * 1024 + gb * 256 + lane * 4] = a0;
            *(float4*)&part[(jc * 2 + 1) * 1024 + gb * 256 + lane * 4] = a1;
        }
        __syncthreads();
        if (t < 512) {        // reduce E + LSTM pointwise
            const int r = t >> 8, d = t & 255;
            float g0 = 0.f, g1 = 0.f, g2 = 0.f, g3 = 0.f;
            #pragma unroll
            for (int jc = 0; jc < 4; ++jc) {
                const int base = (jc * 2 + r) * 1024 + d;
                g0 += part[base];
                g1 += part[base + 256];
                g2 += part[base + 512];
                g3 += part[base + 768];
            }
            const float yt = ytil[r];
            const float gi = g0 + yt * wihs[d]       + biass[d];
            const float gf = g1 + yt * wihs[256 + d] + biass[256 + d];
            const float gg = g2 + yt * wihs[512 + d] + biass[512 + d];
            const float go = g3 + yt * wihs[768 + d] + biass[768 + d];
            const float c_old = hc2[256 + d][r];
            const float cn = fast_sigm(gf) * c_old + fast_sigm(gi) * fast_tanh(gg);
            const float hn = fast_sigm(go) * fast_tanh(cn);
            hc2[d][r] = hn;
            hc2[256 + d][r] = cn;
        }
        __syncthreads();
    }

    // ---- final: out[b] = [h, ctx] . fcf_w + fcf_b
    if (t < 512) {
        const int r = t >> 8, j = t & 255;
        float p = hc2[j][r] * fcfw[j] + ctx[r][j] * fcfw[256 + j];
        #pragma unroll
        for (int off = 32; off; off >>= 1) p += __shfl_xor(p, off);
        if (lane == 0) red[wv] = p;
    }
    __syncthreads();
    if (t < 2)
        out[b0 + t] = red[4 * t] + red[4 * t + 1] + red[4 * t + 2] + red[4 * t + 3] + fcfb[0];
}

extern "C" void kernel_launch(void* const* d_in, const int* in_sizes, int n_in,
                              void* d_out, int out_size, void* d_ws, size_t ws_size,
                              hipStream_t stream) {
    (void)in_sizes; (void)n_in; (void)out_size; (void)ws_size;
    const float* enc   = (const float*)d_in[0];   // [512][128][256]
    const float* yhist = (const float*)d_in[1];   // [512][128]
    const float* w1    = (const float*)d_in[2];   // [768][256]
    const float* b1    = (const float*)d_in[3];   // [256]
    const float* w2    = (const float*)d_in[4];   // [256]
    // d_in[5] = attn_b2: softmax-invariant, unused
    const float* wih   = (const float*)d_in[6];   // [1024]
    const float* whh   = (const float*)d_in[7];   // [1024][256]
    const float* bih   = (const float*)d_in[8];   // [1024]
    const float* bhh   = (const float*)d_in[9];   // [1024]
    const float* fcw   = (const float*)d_in[10];  // [257]
    const float* fcb   = (const float*)d_in[11];  // [1]
    const float* fcfw  = (const float*)d_in[12];  // [512]
    const float* fcfb  = (const float*)d_in[13];  // [1]
    float* out = (float*)d_out;

    float* ws = (float*)d_ws;
    float* pre = ws;                                        // 16777216 f (64 MB)
    unsigned short* w1bf = (unsigned short*)(ws + 16777216);  // 131072 bf16
    unsigned short* whhT = w1bf + 131072;                     // 262144 bf16
    float* biasg = (float*)(whhT + 262144);                   // 1024 f

    prep_w1_bias<<<513, 256, 0, stream>>>(w1, bih, bhh, w1bf, biasg);
    transpose_whh_bf<<<64, 256, 0, stream>>>(whh, whhT);
    pre_enc_kernel<<<8192, 256, 0, stream>>>(enc, w1, b1, pre);
    decoder_main<<<256, 1024, 0, stream>>>(enc, yhist, pre, w1bf, w2, whhT, wih,
                                           biasg, fcw, fcb, fcfw, fcfb, out);
}